// Round 1
// baseline (152.520 us; speedup 1.0000x reference)
//
#include <hip/hip_runtime.h>
#include <math.h>

// Problem constants (fixed by the reference): N=256, H*W=196, KB=512, CTRL=512,
// MEM=512, L=8, NMOD=9.  All inputs/outputs are float32.
constexpr int   NB   = 256;
constexpr int   HW   = 196;
constexpr int   KBC  = 512;
constexpr int   LSZ  = 8;
constexpr float EPSF = 1e-12f;

// ---------------- workspace layout (floats) ----------------
constexpr size_t S_ATT    = (size_t)NB * HW;                  // 50176
constexpr size_t OFF_ATT1 = 0;
constexpr size_t OFF_ATT2 = OFF_ATT1 + S_ATT;
constexpr size_t OFF_W1   = OFF_ATT2 + S_ATT;
constexpr size_t OFF_W2   = OFF_W1   + S_ATT;
constexpr size_t OFF_AF   = OFF_W2   + S_ATT;
constexpr size_t OFF_AT   = OFF_AF   + S_ATT;
constexpr size_t OFF_AS   = OFF_AT   + S_ATT;
constexpr size_t OFF_C1   = OFF_AS   + S_ATT;                 // 256 x 2048 (c_find|c_tr|c_d1|c_d2)
constexpr size_t OFF_KPART= OFF_C1   + (size_t)NB*2048;       // 4 x 256 x 1024 katt partials
constexpr size_t OFF_G    = OFF_KPART+ (size_t)4*NB*1024;     // 256 x 512 (c_tr * katt2)
constexpr size_t OFF_A1   = OFF_G    + (size_t)NB*KBC;        // 256 x 1536
constexpr size_t OFF_A2   = OFF_A1   + (size_t)NB*1536;       // 256 x 1536
constexpr size_t OFF_C2   = OFF_A2   + (size_t)NB*1536;       // 256 x 1024 (mem1|mem2)
constexpr size_t OFF_PF   = OFF_C2   + (size_t)NB*1024;       // 256 x 8 move_fw(ptr)
constexpr size_t OFF_PB   = OFF_PF   + (size_t)NB*LSZ;        // 256 x 8 move_bw(ptr)
constexpr size_t OFF_PFB  = OFF_PB   + (size_t)NB*LSZ;        // 256 x 8 move_bw(move_fw(ptr))
constexpr size_t OFF_SF2  = OFF_PFB  + (size_t)NB*LSZ;        // 256  sum f^2
constexpr size_t OFF_SFFB = OFF_SF2  + NB;                    // 256  sum f*fb
constexpr size_t WS_FLOATS= OFF_SFFB + NB;

static __device__ __forceinline__ float4 ld4(const float* p) {
    return *reinterpret_cast<const float4*>(p);
}

// ================================================================
// Kernel 1: per-n ptr variants, stack reads att1/att2, spatial softmax
// grid = 256 blocks (one per n), 256 threads
// ================================================================
__global__ __launch_bounds__(256) void k_att(
    const float* __restrict__ stk, const float* __restrict__ ptrp,
    float* __restrict__ att1g, float* __restrict__ att2g,
    float* __restrict__ w1g, float* __restrict__ w2g,
    float* __restrict__ fws, float* __restrict__ bws, float* __restrict__ fbws,
    float* __restrict__ sf2ws, float* __restrict__ sffbws)
{
    const int n = blockIdx.x;
    const int t = threadIdx.x;
    float pp[8], f[8], b[8], fb[8];
#pragma unroll
    for (int l = 0; l < 8; ++l) pp[l] = ptrp[n*8 + l];
    // move_fw: f[0]=0, f[l]=pp[l-1], f[7]+=pp[7]
    f[0] = 0.f;
#pragma unroll
    for (int l = 1; l < 8; ++l) f[l] = pp[l-1];
    f[7] += pp[7];
    // move_bw: b[l]=pp[l+1], b[7]=0, b[0]+=pp[0]
#pragma unroll
    for (int l = 0; l < 7; ++l) b[l] = pp[l+1];
    b[7] = 0.f;
    b[0] += pp[0];
    // move_bw(move_fw): fb[l]=f[l+1], fb[7]=0, fb[0]+=f[0]
#pragma unroll
    for (int l = 0; l < 7; ++l) fb[l] = f[l+1];
    fb[7] = 0.f;
    fb[0] += f[0];

    if (t == 0) {
        float sf2 = 0.f, sffb = 0.f;
#pragma unroll
        for (int l = 0; l < 8; ++l) {
            fws[n*8+l] = f[l]; bws[n*8+l] = b[l]; fbws[n*8+l] = fb[l];
            sf2  += f[l]*f[l];
            sffb += f[l]*fb[l];
        }
        sf2ws[n] = sf2; sffbws[n] = sffb;
    }

    float a1 = 0.f, a2 = 0.f;
    if (t < HW) {
        const float* sp = stk + ((size_t)n*HW + t) * 8;
        float4 v0 = ld4(sp), v1 = ld4(sp + 4);
        float s[8] = {v0.x, v0.y, v0.z, v0.w, v1.x, v1.y, v1.z, v1.w};
#pragma unroll
        for (int l = 0; l < 8; ++l) {
            a2 = fmaf(s[l], pp[l], a2);   // read(stk, ptr)
            a1 = fmaf(s[l],  b[l], a1);   // read(stk, move_bw(ptr))
        }
        att1g[n*HW + t] = a1;
        att2g[n*HW + t] = a2;
    }

    __shared__ float red[256];
    // softmax over 196 pixels for att1
    red[t] = (t < HW) ? a1 : -3.0e38f;
    __syncthreads();
    for (int off = 128; off > 0; off >>= 1) { if (t < off) red[t] = fmaxf(red[t], red[t+off]); __syncthreads(); }
    const float m1 = red[0];
    __syncthreads();
    float e1 = (t < HW) ? __expf(a1 - m1) : 0.f;
    red[t] = e1;
    __syncthreads();
    for (int off = 128; off > 0; off >>= 1) { if (t < off) red[t] += red[t+off]; __syncthreads(); }
    const float s1 = red[0];
    __syncthreads();
    if (t < HW) w1g[n*HW + t] = e1 / s1;

    // softmax for att2
    red[t] = (t < HW) ? a2 : -3.0e38f;
    __syncthreads();
    for (int off = 128; off > 0; off >>= 1) { if (t < off) red[t] = fmaxf(red[t], red[t+off]); __syncthreads(); }
    const float m2 = red[0];
    __syncthreads();
    float e2 = (t < HW) ? __expf(a2 - m2) : 0.f;
    red[t] = e2;
    __syncthreads();
    for (int off = 128; off > 0; off >>= 1) { if (t < off) red[t] += red[t+off]; __syncthreads(); }
    const float s2 = red[0];
    __syncthreads();
    if (t < HW) w2g[n*HW + t] = e2 / s2;
}

// ================================================================
// Generic tiled f32 GEMM: C[M x Ntot] = A[M x K] @ B + bias, where the
// B/bias (and optionally A) pointer is selected per 512-column group.
// 256 threads/block. BM/TM x BN/TN == 256.
// ================================================================
template<int BM, int BN, int BK, int TM, int TN, int K>
__global__ __launch_bounds__(256) void gemm_f32(
    const float* __restrict__ Aa, const float* __restrict__ Ab,
    const float* __restrict__ B0, const float* __restrict__ B1,
    const float* __restrict__ B2, const float* __restrict__ B3,
    const float* __restrict__ bias0, const float* __restrict__ bias1,
    const float* __restrict__ bias2, const float* __restrict__ bias3,
    float* __restrict__ C, int Ntot)
{
    constexpr int TX = BN / TN;
    constexpr int TY = BM / TM;
    static_assert(TX * TY == 256, "bad tile");
    const int t  = threadIdx.x;
    const int tx = t % TX, ty = t / TX;
    const int bn = blockIdx.x * BN;
    const int bm = blockIdx.y * BM;
    const int mat = bn >> 9;                              // column-group -> which weight matrix
    const float* Bsel = (mat == 0) ? B0 : (mat == 1) ? B1 : (mat == 2) ? B2 : B3;
    const float* bsel = (mat == 0) ? bias0 : (mat == 1) ? bias1 : (mat == 2) ? bias2 : bias3;
    const float* A = (mat != 0 && Ab != nullptr) ? Ab : Aa;
    const int bnm = bn & 511;

    __shared__ float As[BK][BM + 4];
    __shared__ float Bs[BK][BN + 4];
    float acc[TM][TN] = {};

    for (int kk = 0; kk < K; kk += BK) {
        constexpr int AN4 = BM * BK / 4;
        for (int q = t; q < AN4; q += 256) {
            const int r  = q / (BK/4);
            const int c4 = (q % (BK/4)) * 4;
            float4 v = ld4(&A[(size_t)(bm + r) * K + kk + c4]);
            As[c4+0][r] = v.x; As[c4+1][r] = v.y; As[c4+2][r] = v.z; As[c4+3][r] = v.w;
        }
        constexpr int BN4 = BK * BN / 4;
        for (int q = t; q < BN4; q += 256) {
            const int r  = q / (BN/4);
            const int c4 = (q % (BN/4)) * 4;
            float4 v = ld4(&Bsel[(size_t)(kk + r) * 512 + bnm + c4]);
            *reinterpret_cast<float4*>(&Bs[r][c4]) = v;
        }
        __syncthreads();
#pragma unroll
        for (int k = 0; k < BK; ++k) {
            float ra[TM], rb[TN];
            if constexpr (TM == 2) {
                float2 v = *reinterpret_cast<const float2*>(&As[k][ty*TM]);
                ra[0] = v.x; ra[1] = v.y;
            } else {
#pragma unroll
                for (int i = 0; i < TM; ++i) ra[i] = As[k][ty*TM + i];
            }
            if constexpr (TN == 4) {
                float4 v = *reinterpret_cast<const float4*>(&Bs[k][tx*TN]);
                rb[0]=v.x; rb[1]=v.y; rb[2]=v.z; rb[3]=v.w;
            } else if constexpr (TN == 2) {
                float2 v = *reinterpret_cast<const float2*>(&Bs[k][tx*TN]);
                rb[0]=v.x; rb[1]=v.y;
            } else {
#pragma unroll
                for (int j = 0; j < TN; ++j) rb[j] = Bs[k][tx*TN + j];
            }
#pragma unroll
            for (int i = 0; i < TM; ++i)
#pragma unroll
                for (int j = 0; j < TN; ++j)
                    acc[i][j] = fmaf(ra[i], rb[j], acc[i][j]);
        }
        __syncthreads();
    }
#pragma unroll
    for (int i = 0; i < TM; ++i) {
        const size_t row = bm + ty*TM + i;
#pragma unroll
        for (int j = 0; j < TN; ++j) {
            const int col = bn + tx*TN + j;
            C[row * (size_t)Ntot + col] = acc[i][j] + bsel[bnm + tx*TN + j];
        }
    }
}

// ================================================================
// Kernel 3: first pass over kb.
//   per pixel: Find dot/norm (with c_find), Scene dot/norm
//   per (n,k): katt1/katt2 weighted sums with softmax weights w1/w2
// grid = 256*4 blocks (4 pixel-splits per n), 256 threads (4 waves).
// wave handles whole pixels; lane l owns channels l*8..l*8+7.
// ================================================================
__global__ __launch_bounds__(256) void k_kbA(
    const float* __restrict__ kb, const float* __restrict__ C1,
    const float* __restrict__ w_find, const float* __restrict__ b_find,
    const float* __restrict__ w_scene, const float* __restrict__ b_scene,
    const float* __restrict__ w1g, const float* __restrict__ w2g,
    float* __restrict__ aF, float* __restrict__ aS, float* __restrict__ kpart)
{
    const int blk = blockIdx.x;
    const int n = blk >> 2, sp = blk & 3;
    const int t = threadIdx.x, wv = t >> 6, lane = t & 63;
    const int k0 = lane * 8;
    const int p0 = sp * 49;

    __shared__ float w1s[49], w2s[49];
    __shared__ float kred[4][1024];
    if (t < 49) { w1s[t] = w1g[n*HW + p0 + t]; w2s[t] = w2g[n*HW + p0 + t]; }
    __syncthreads();

    float cf[8], wf[8], wsc[8];
    {
        float4 a0 = ld4(C1 + (size_t)n*2048 + k0), a1 = ld4(C1 + (size_t)n*2048 + k0 + 4);
        cf[0]=a0.x; cf[1]=a0.y; cf[2]=a0.z; cf[3]=a0.w; cf[4]=a1.x; cf[5]=a1.y; cf[6]=a1.z; cf[7]=a1.w;
        float4 b0 = ld4(w_find + k0), b1 = ld4(w_find + k0 + 4);
        wf[0]=b0.x; wf[1]=b0.y; wf[2]=b0.z; wf[3]=b0.w; wf[4]=b1.x; wf[5]=b1.y; wf[6]=b1.z; wf[7]=b1.w;
        float4 c0 = ld4(w_scene + k0), c1 = ld4(w_scene + k0 + 4);
        wsc[0]=c0.x; wsc[1]=c0.y; wsc[2]=c0.z; wsc[3]=c0.w; wsc[4]=c1.x; wsc[5]=c1.y; wsc[6]=c1.z; wsc[7]=c1.w;
    }
    const float bf = b_find[0], bs = b_scene[0];

    float k1a[8] = {0,0,0,0,0,0,0,0};
    float k2a[8] = {0,0,0,0,0,0,0,0};

    for (int pl = wv; pl < 49; pl += 4) {
        const float* src = kb + (((size_t)n*HW + p0 + pl) * KBC + k0);
        float4 v0 = ld4(src), v1 = ld4(src + 4);
        float kv[8] = {v0.x, v0.y, v0.z, v0.w, v1.x, v1.y, v1.z, v1.w};
        float sA = 0.f, sB = 0.f, sE = 0.f, sF = 0.f;
#pragma unroll
        for (int j = 0; j < 8; ++j) {
            const float t1 = kv[j] * cf[j];
            sA = fmaf(t1, t1, sA);
            sB = fmaf(t1, wf[j], sB);
            sE = fmaf(kv[j], kv[j], sE);
            sF = fmaf(kv[j], wsc[j], sF);
        }
        const float w1p = w1s[pl], w2p = w2s[pl];
#pragma unroll
        for (int j = 0; j < 8; ++j) {
            k1a[j] = fmaf(w1p, kv[j], k1a[j]);
            k2a[j] = fmaf(w2p, kv[j], k2a[j]);
        }
#pragma unroll
        for (int m = 1; m < 64; m <<= 1) {
            sA += __shfl_xor(sA, m);
            sB += __shfl_xor(sB, m);
            sE += __shfl_xor(sE, m);
            sF += __shfl_xor(sF, m);
        }
        if (lane == 0) {
            const size_t p = (size_t)n*HW + p0 + pl;
            aF[p] = sB / fmaxf(sqrtf(sA), EPSF) + bf;
            aS[p] = sF / fmaxf(sqrtf(sE), EPSF) + bs;
        }
    }
#pragma unroll
    for (int j = 0; j < 8; ++j) { kred[wv][k0 + j] = k1a[j]; kred[wv][512 + k0 + j] = k2a[j]; }
    __syncthreads();
    for (int idx = t; idx < 1024; idx += 256) {
        const float s = kred[0][idx] + kred[1][idx] + kred[2][idx] + kred[3][idx];
        kpart[((size_t)sp*NB + n) * 1024 + idx] = s;
    }
}

// ================================================================
// Kernel 4: reduce katt partials; build g = c_tr*katt2; l2-normalized
// elt1/elt2; assemble concat matrices A1=[ctrl|elt1|katt2], A2=[ctrl|elt2|katt1]
// grid = 256 blocks (per n), 256 threads.
// ================================================================
__global__ __launch_bounds__(256) void k_elt(
    const float* __restrict__ kpart, const float* __restrict__ C1,
    const float* __restrict__ control,
    float* __restrict__ g, float* __restrict__ A1, float* __restrict__ A2)
{
    const int n = blockIdx.x;
    const int t = threadIdx.x;
    __shared__ float k1s[512], k2s[512];
    for (int idx = t; idx < 512; idx += 256) {
        float s1 = 0.f, s2 = 0.f;
#pragma unroll
        for (int sp = 0; sp < 4; ++sp) {
            const float* base = kpart + ((size_t)sp*NB + n) * 1024;
            s1 += base[idx];
            s2 += base[512 + idx];
        }
        k1s[idx] = s1; k2s[idx] = s2;
    }
    __syncthreads();

    float v1[2], v2[2];
    float sum1 = 0.f, sum2 = 0.f;
#pragma unroll
    for (int i = 0; i < 2; ++i) {
        const int k = t + i*256;
        const float ct  = C1[(size_t)n*2048 + 512  + k];
        const float cd1 = C1[(size_t)n*2048 + 1024 + k];
        const float cd2 = C1[(size_t)n*2048 + 1536 + k];
        g[(size_t)n*512 + k] = ct * k2s[k];
        v1[i] = cd1 * k2s[k];
        v2[i] = cd2 * k1s[k] * k2s[k];
        sum1 = fmaf(v1[i], v1[i], sum1);
        sum2 = fmaf(v2[i], v2[i], sum2);
    }
    __shared__ float r1[256], r2[256];
    r1[t] = sum1; r2[t] = sum2;
    __syncthreads();
    for (int off = 128; off > 0; off >>= 1) {
        if (t < off) { r1[t] += r1[t+off]; r2[t] += r2[t+off]; }
        __syncthreads();
    }
    const float n1 = fmaxf(sqrtf(r1[0]), EPSF);
    const float n2 = fmaxf(sqrtf(r2[0]), EPSF);
#pragma unroll
    for (int i = 0; i < 2; ++i) {
        const int k = t + i*256;
        const float c = control[(size_t)n*512 + k];
        A1[(size_t)n*1536 + k]        = c;
        A1[(size_t)n*1536 + 512 + k]  = v1[i] / n1;
        A1[(size_t)n*1536 + 1024 + k] = k2s[k];
        A2[(size_t)n*1536 + k]        = c;
        A2[(size_t)n*1536 + 512 + k]  = v2[i] / n2;
        A2[(size_t)n*1536 + 1024 + k] = k1s[k];
    }
}

// ================================================================
// Kernel 5: second pass over kb — Transform attention (needs g).
// grid = 256*4 blocks, 256 threads.
// ================================================================
__global__ __launch_bounds__(256) void k_kbB(
    const float* __restrict__ kb, const float* __restrict__ g,
    const float* __restrict__ w_tr, const float* __restrict__ b_tr,
    float* __restrict__ aT)
{
    const int blk = blockIdx.x;
    const int n = blk >> 2, sp = blk & 3;
    const int t = threadIdx.x, wv = t >> 6, lane = t & 63;
    const int k0 = lane * 8;
    const int p0 = sp * 49;
    float gv[8], wt[8];
    {
        float4 a0 = ld4(g + (size_t)n*512 + k0), a1 = ld4(g + (size_t)n*512 + k0 + 4);
        gv[0]=a0.x; gv[1]=a0.y; gv[2]=a0.z; gv[3]=a0.w; gv[4]=a1.x; gv[5]=a1.y; gv[6]=a1.z; gv[7]=a1.w;
        float4 b0 = ld4(w_tr + k0), b1 = ld4(w_tr + k0 + 4);
        wt[0]=b0.x; wt[1]=b0.y; wt[2]=b0.z; wt[3]=b0.w; wt[4]=b1.x; wt[5]=b1.y; wt[6]=b1.z; wt[7]=b1.w;
    }
    const float bt = b_tr[0];
    for (int pl = wv; pl < 49; pl += 4) {
        const float* src = kb + (((size_t)n*HW + p0 + pl) * KBC + k0);
        float4 v0 = ld4(src), v1 = ld4(src + 4);
        float kv[8] = {v0.x, v0.y, v0.z, v0.w, v1.x, v1.y, v1.z, v1.w};
        float sC = 0.f, sD = 0.f;
#pragma unroll
        for (int j = 0; j < 8; ++j) {
            const float u = kv[j] * gv[j];
            sC = fmaf(u, u, sC);
            sD = fmaf(u, wt[j], sD);
        }
#pragma unroll
        for (int m = 1; m < 64; m <<= 1) { sC += __shfl_xor(sC, m); sD += __shfl_xor(sD, m); }
        if (lane == 0) aT[(size_t)n*HW + p0 + pl] = sD / fmaxf(sqrtf(sC), EPSF) + bt;
    }
}

// ================================================================
// Kernel 7: mem_avg = p0*mem_prev + p7*mem1 + p8*mem2  (C2 already has biases)
// ================================================================
__global__ __launch_bounds__(256) void k_memout(
    const float* __restrict__ C2, const float* __restrict__ memprev,
    const float* __restrict__ prob, float* __restrict__ out_mem)
{
    const int idx = blockIdx.x * 256 + threadIdx.x;   // < 256*512
    const int n = idx >> 9, j = idx & 511;
    const float p0 = prob[n*9 + 0], p7 = prob[n*9 + 7], p8 = prob[n*9 + 8];
    out_mem[idx] = p0 * memprev[idx]
                 + p7 * C2[(size_t)n*1024 + j]
                 + p8 * C2[(size_t)n*1024 + 512 + j];
}

// ================================================================
// Kernel 8: assemble att_stack_avg (all 9 modules, Filter expanded
// algebraically) and stack_ptr_avg (weighted ptrs + softmax sharpen).
// grid = 256 blocks (per n), 256 threads (one pixel each).
// ================================================================
__global__ __launch_bounds__(256) void k_assemble(
    const float* __restrict__ stk, const float* __restrict__ ptrp,
    const float* __restrict__ prob,
    const float* __restrict__ att1g, const float* __restrict__ att2g,
    const float* __restrict__ aFg, const float* __restrict__ aTg, const float* __restrict__ aSg,
    const float* __restrict__ fws, const float* __restrict__ bws, const float* __restrict__ fbws,
    const float* __restrict__ sf2ws, const float* __restrict__ sffbws,
    float* __restrict__ out_att, float* __restrict__ out_ptr)
{
    const int n = blockIdx.x;
    const int t = threadIdx.x;
    __shared__ float pp[8], f[8], b[8], fb[8], pr[9], sc2[2];
    if (t < 8) { pp[t] = ptrp[n*8+t]; f[t] = fws[n*8+t]; b[t] = bws[n*8+t]; fb[t] = fbws[n*8+t]; }
    if (t < 9) pr[t] = prob[n*9+t];
    if (t == 0) { sc2[0] = sf2ws[n]; sc2[1] = sffbws[n]; }
    __syncthreads();

    if (t < HW) {
        const size_t p = (size_t)n*HW + t;
        const float* spt = stk + p*8;
        float4 v0 = ld4(spt), v1 = ld4(spt+4);
        float s[8] = {v0.x, v0.y, v0.z, v0.w, v1.x, v1.y, v1.z, v1.w};
        const float a1 = att1g[p], a2 = att2g[p];
        const float vaF = aFg[p], vaT = aTg[p], vaS = aSg[p];
        const float mn = fminf(a1, a2), mx = fmaxf(a1, a2);
        // Filter = And(Find(...)) expanded:
        //   stk1[l]   = aF*f[l] + s[l]*(1-f[l])
        //   att2' = read(stk1,f)  = aF*Σf²   + Σ s·f  − Σ s·f²
        //   att1' = read(stk1,fb) = aF*Σf·fb + Σ s·fb − Σ s·f·fb
        float rf = 0.f, rf2 = 0.f, rfb = 0.f, rffb = 0.f;
#pragma unroll
        for (int l = 0; l < 8; ++l) {
            rf   = fmaf(s[l], f[l],        rf);
            rf2  = fmaf(s[l], f[l]*f[l],   rf2);
            rfb  = fmaf(s[l], fb[l],       rfb);
            rffb = fmaf(s[l], f[l]*fb[l],  rffb);
        }
        const float att2p = vaF*sc2[0] + rf  - rf2;
        const float att1p = vaF*sc2[1] + rfb - rffb;
        const float mnF = fminf(att1p, att2p);
        const float c48 = pr[4] + pr[8];           // And and DescribeTwo share the same stack update
        float o[8];
#pragma unroll
        for (int l = 0; l < 8; ++l) {
            const float sl = s[l];
            const float stkF = vaF*f[l] + sl*(1.f - f[l]);
            float r = (pr[0] + pr[7]) * sl;                               // NoOp + DescribeOne
            r = fmaf(pr[1], stkF, r);                                     // Find
            r = fmaf(pr[2], vaT*pp[l] + sl*(1.f - pp[l]), r);             // Transform
            r = fmaf(pr[3], mnF*fb[l] + stkF*(1.f - fb[l]), r);           // Filter
            r = fmaf(c48,   mn*b[l] + sl*(1.f - b[l]), r);                // And + DescribeTwo
            r = fmaf(pr[5], mx*b[l] + sl*(1.f - b[l]), r);                // Or
            r = fmaf(pr[6], vaS*f[l] + sl*(1.f - f[l]), r);               // Scene
            o[l] = r;
        }
        *reinterpret_cast<float4*>(out_att + p*8)     = make_float4(o[0], o[1], o[2], o[3]);
        *reinterpret_cast<float4*>(out_att + p*8 + 4) = make_float4(o[4], o[5], o[6], o[7]);
    }

    if (t == 0) {
        const float cpp = pr[0] + pr[2] + pr[7];
        const float cf  = pr[1] + pr[6];
        const float cb  = pr[4] + pr[5] + pr[8];
        float pa[8];
        float m = -3.0e38f;
#pragma unroll
        for (int l = 0; l < 8; ++l) {
            pa[l] = cpp*pp[l] + cf*f[l] + cb*b[l] + pr[3]*fb[l];
            m = fmaxf(m, pa[l]);
        }
        float ssum = 0.f;
#pragma unroll
        for (int l = 0; l < 8; ++l) { pa[l] = __expf(pa[l] - m); ssum += pa[l]; }
#pragma unroll
        for (int l = 0; l < 8; ++l) out_ptr[n*8 + l] = pa[l] / ssum;
    }
}

// ================================================================
extern "C" void kernel_launch(void* const* d_in, const int* in_sizes, int n_in,
                              void* d_out, int out_size, void* d_ws, size_t ws_size,
                              hipStream_t stream)
{
    (void)in_sizes; (void)n_in; (void)out_size;
    const float* control = (const float*)d_in[0];
    const float* kb      = (const float*)d_in[1];
    const float* prob    = (const float*)d_in[2];
    const float* memprev = (const float*)d_in[3];
    const float* stk     = (const float*)d_in[4];
    const float* ptrp    = (const float*)d_in[5];
    const float* find_w  = (const float*)d_in[6];
    const float* find_b  = (const float*)d_in[7];
    const float* findc_w = (const float*)d_in[8];
    const float* findc_b = (const float*)d_in[9];
    const float* tr_w    = (const float*)d_in[10];
    const float* tr_b    = (const float*)d_in[11];
    const float* trc_w   = (const float*)d_in[12];
    const float* trc_b   = (const float*)d_in[13];
    const float* sc_w    = (const float*)d_in[14];
    const float* sc_b    = (const float*)d_in[15];
    const float* d1_w    = (const float*)d_in[16];
    const float* d1_b    = (const float*)d_in[17];
    const float* d1m_w   = (const float*)d_in[18];
    const float* d1m_b   = (const float*)d_in[19];
    const float* d2_w    = (const float*)d_in[20];
    const float* d2_b    = (const float*)d_in[21];
    const float* d2m_w   = (const float*)d_in[22];
    const float* d2m_b   = (const float*)d_in[23];

    if (ws_size < WS_FLOATS * sizeof(float)) return;  // would fail validation loudly

    float* ws    = (float*)d_ws;
    float* att1g = ws + OFF_ATT1;
    float* att2g = ws + OFF_ATT2;
    float* w1g   = ws + OFF_W1;
    float* w2g   = ws + OFF_W2;
    float* aF    = ws + OFF_AF;
    float* aT    = ws + OFF_AT;
    float* aS    = ws + OFF_AS;
    float* C1    = ws + OFF_C1;
    float* kpart = ws + OFF_KPART;
    float* g     = ws + OFF_G;
    float* A1    = ws + OFF_A1;
    float* A2    = ws + OFF_A2;
    float* C2    = ws + OFF_C2;
    float* fws   = ws + OFF_PF;
    float* bws   = ws + OFF_PB;
    float* fbws  = ws + OFF_PFB;
    float* sf2   = ws + OFF_SF2;
    float* sffb  = ws + OFF_SFFB;

    float* out_att = (float*)d_out;                       // N*H*W*L
    float* out_ptr = out_att + (size_t)NB*HW*LSZ;         // N*L
    float* out_mem = out_ptr + (size_t)NB*LSZ;            // N*MEM

    // 1. stack reads + softmax weights + ptr variants
    k_att<<<NB, 256, 0, stream>>>(stk, ptrp, att1g, att2g, w1g, w2g,
                                  fws, bws, fbws, sf2, sffb);
    // 2. C1 = control @ [find_ci|transform_ci|describeone_ci|describetwo_ci] + biases
    gemm_f32<32, 64, 16, 2, 4, 512><<<dim3(32, 8), 256, 0, stream>>>(
        control, nullptr,
        find_w, tr_w, d1_w, d2_w,
        find_b, tr_b, d1_b, d2_b,
        C1, 2048);
    // 3. kb pass A: Find/Scene attentions + katt partial sums
    k_kbA<<<NB*4, 256, 0, stream>>>(kb, C1, findc_w, findc_b, sc_w, sc_b,
                                    w1g, w2g, aF, aS, kpart);
    // 4. katt reduce, g, elt norms, concat matrices
    k_elt<<<NB, 256, 0, stream>>>(kpart, C1, control, g, A1, A2);
    // 5. kb pass B: Transform attention
    k_kbB<<<NB*4, 256, 0, stream>>>(kb, g, trc_w, trc_b, aT);
    // 6. C2 = [A1 @ d1m_w | A2 @ d2m_w] + biases
    gemm_f32<32, 32, 16, 2, 2, 1536><<<dim3(32, 8), 256, 0, stream>>>(
        A1, A2,
        d1m_w, d2m_w, d1m_w, d2m_w,
        d1m_b, d2m_b, d1m_b, d2m_b,
        C2, 1024);
    // 7. mem_avg
    k_memout<<<(NB*512)/256, 256, 0, stream>>>(C2, memprev, prob, out_mem);
    // 8. att_stack_avg + stack_ptr_avg
    k_assemble<<<NB, 256, 0, stream>>>(stk, ptrp, prob, att1g, att2g, aF, aT, aS,
                                       fws, bws, fbws, sf2, sffb, out_att, out_ptr);
}

// Round 2
// 92.551 us; speedup vs baseline: 1.6479x; 1.6479x over previous
//
#include <hip/hip_runtime.h>
#include <math.h>

// Problem constants: N=256, H*W=196, KB=512, CTRL=512, MEM=512, L=8, NMOD=9. f32.
constexpr int   NB   = 256;
constexpr int   HW   = 196;
constexpr int   KBC  = 512;
constexpr int   LSZ  = 8;
constexpr float EPSF = 1e-12f;

// ---------------- workspace layout (floats) ----------------
// Proven available: >= 12.44 MB (round-1 layout passed). This layout: 11.92 MB.
constexpr size_t S_ATT    = (size_t)NB * HW;                  // 50176
constexpr size_t OFF_ATT1 = 0;
constexpr size_t OFF_ATT2 = OFF_ATT1 + S_ATT;
constexpr size_t OFF_W1   = OFF_ATT2 + S_ATT;
constexpr size_t OFF_W2   = OFF_W1   + S_ATT;
constexpr size_t OFF_AF   = OFF_W2   + S_ATT;
constexpr size_t OFF_AT   = OFF_AF   + S_ATT;
constexpr size_t OFF_AS   = OFF_AT   + S_ATT;
constexpr size_t OFF_C1   = OFF_AS   + S_ATT;                 // 256 x 2048
// Window at OFF_A1 of 2,097,152 floats serves three non-overlapping-in-time uses:
//   (a) gemm1 split-K partials [4][256][2048]  (before reduce1)
//   (b) A1/A2/G                                 (after k_elt)
//   (c) SCRATCH: kbA kpart [4][256][1024] then gemm2 partials [8][256][512]
constexpr size_t OFF_A1   = OFF_C1 + (size_t)NB*2048;         // 256 x 1536
constexpr size_t OFF_A2   = OFF_A1 + (size_t)NB*1536;         // 256 x 1536
constexpr size_t OFF_G    = OFF_A2 + (size_t)NB*1536;         // 256 x 512
constexpr size_t OFF_SCR  = OFF_G  + (size_t)NB*512;          // 1,048,576 + 131,072 pad
constexpr size_t OFF_PF   = OFF_SCR + 1048576 + 131072;
constexpr size_t OFF_PB   = OFF_PF   + (size_t)NB*LSZ;
constexpr size_t OFF_PFB  = OFF_PB   + (size_t)NB*LSZ;
constexpr size_t OFF_SF2  = OFF_PFB  + (size_t)NB*LSZ;
constexpr size_t OFF_SFFB = OFF_SF2  + NB;
constexpr size_t WS_FLOATS= OFF_SFFB + NB;

static __device__ __forceinline__ float4 ld4(const float* p) {
    return *reinterpret_cast<const float4*>(p);
}

// ================================================================
// Kernel 1: per-n ptr variants, stack reads att1/att2, spatial softmax
// ================================================================
__global__ __launch_bounds__(256) void k_att(
    const float* __restrict__ stk, const float* __restrict__ ptrp,
    float* __restrict__ att1g, float* __restrict__ att2g,
    float* __restrict__ w1g, float* __restrict__ w2g,
    float* __restrict__ fws, float* __restrict__ bws, float* __restrict__ fbws,
    float* __restrict__ sf2ws, float* __restrict__ sffbws)
{
    const int n = blockIdx.x;
    const int t = threadIdx.x;
    float pp[8], f[8], b[8], fb[8];
#pragma unroll
    for (int l = 0; l < 8; ++l) pp[l] = ptrp[n*8 + l];
    f[0] = 0.f;
#pragma unroll
    for (int l = 1; l < 8; ++l) f[l] = pp[l-1];
    f[7] += pp[7];
#pragma unroll
    for (int l = 0; l < 7; ++l) b[l] = pp[l+1];
    b[7] = 0.f;
    b[0] += pp[0];
#pragma unroll
    for (int l = 0; l < 7; ++l) fb[l] = f[l+1];
    fb[7] = 0.f;
    fb[0] += f[0];

    if (t == 0) {
        float sf2 = 0.f, sffb = 0.f;
#pragma unroll
        for (int l = 0; l < 8; ++l) {
            fws[n*8+l] = f[l]; bws[n*8+l] = b[l]; fbws[n*8+l] = fb[l];
            sf2  += f[l]*f[l];
            sffb += f[l]*fb[l];
        }
        sf2ws[n] = sf2; sffbws[n] = sffb;
    }

    float a1 = 0.f, a2 = 0.f;
    if (t < HW) {
        const float* sp = stk + ((size_t)n*HW + t) * 8;
        float4 v0 = ld4(sp), v1 = ld4(sp + 4);
        float s[8] = {v0.x, v0.y, v0.z, v0.w, v1.x, v1.y, v1.z, v1.w};
#pragma unroll
        for (int l = 0; l < 8; ++l) {
            a2 = fmaf(s[l], pp[l], a2);
            a1 = fmaf(s[l],  b[l], a1);
        }
        att1g[n*HW + t] = a1;
        att2g[n*HW + t] = a2;
    }

    __shared__ float red[256];
    red[t] = (t < HW) ? a1 : -3.0e38f;
    __syncthreads();
    for (int off = 128; off > 0; off >>= 1) { if (t < off) red[t] = fmaxf(red[t], red[t+off]); __syncthreads(); }
    const float m1 = red[0];
    __syncthreads();
    float e1 = (t < HW) ? __expf(a1 - m1) : 0.f;
    red[t] = e1;
    __syncthreads();
    for (int off = 128; off > 0; off >>= 1) { if (t < off) red[t] += red[t+off]; __syncthreads(); }
    const float s1 = red[0];
    __syncthreads();
    if (t < HW) w1g[n*HW + t] = e1 / s1;

    red[t] = (t < HW) ? a2 : -3.0e38f;
    __syncthreads();
    for (int off = 128; off > 0; off >>= 1) { if (t < off) red[t] = fmaxf(red[t], red[t+off]); __syncthreads(); }
    const float m2 = red[0];
    __syncthreads();
    float e2 = (t < HW) ? __expf(a2 - m2) : 0.f;
    red[t] = e2;
    __syncthreads();
    for (int off = 128; off > 0; off >>= 1) { if (t < off) red[t] += red[t+off]; __syncthreads(); }
    const float s2 = red[0];
    __syncthreads();
    if (t < HW) w2g[n*HW + t] = e2 / s2;
}

// ================================================================
// Split-K f32 GEMM, BM=BN=64, BK=16, TM=TN=4, 256 threads.
// Writes raw partials P[ks][256][NTOT] (bias added in reduce).
// SELKS=false: A=A0 (stride ASTR), B selected by column group (bn>>9).
// SELKS=true : fused mem GEMM — A/B selected by ks>>2 (A1',W1 | A2',W2).
// ================================================================
template<int KCHUNK, bool SELKS, int ASTR, int NTOT>
__global__ __launch_bounds__(256) void gemm_sk(
    const float* __restrict__ A0, const float* __restrict__ A1p,
    const float* __restrict__ B0, const float* __restrict__ B1,
    const float* __restrict__ B2, const float* __restrict__ B3,
    float* __restrict__ P)
{
    const int t  = threadIdx.x;
    const int tx = t & 15, ty = t >> 4;
    const int bn = blockIdx.x * 64;
    const int bm = blockIdx.y * 64;
    const int ks = blockIdx.z;

    const float* A; const float* B; int kbase; int bcol;
    if constexpr (SELKS) {
        const int mat = ks >> 2;
        A = mat ? A1p : A0;
        B = mat ? B1 : B0;
        kbase = ks * KCHUNK - mat * (4 * KCHUNK);
        bcol = bn;
    } else {
        const int mat = bn >> 9;
        A = A0;
        B = (mat == 0) ? B0 : (mat == 1) ? B1 : (mat == 2) ? B2 : B3;
        kbase = ks * KCHUNK;
        bcol = bn & 511;
    }
    constexpr int NT = KCHUNK / 16;

    __shared__ float As[16][68];
    __shared__ float Bs[16][68];
    float acc[4][4] = {};

    const int ar = t >> 2, ac4 = (t & 3) * 4;     // A loader: 64 rows x 16 k
    const int br = t >> 4, bc4 = (t & 15) * 4;    // B loader: 16 rows x 64 cols
    const float* Aptr = A + (size_t)(bm + ar) * ASTR + kbase + ac4;
    const float* Bptr = B + (size_t)(kbase + br) * 512 + bcol + bc4;

    float4 aR = ld4(Aptr), bR = ld4(Bptr);
    for (int tile = 0; tile < NT; ++tile) {
        As[ac4+0][ar] = aR.x; As[ac4+1][ar] = aR.y; As[ac4+2][ar] = aR.z; As[ac4+3][ar] = aR.w;
        *reinterpret_cast<float4*>(&Bs[br][bc4]) = bR;
        __syncthreads();
        if (tile + 1 < NT) {                       // prefetch next tile under compute
            aR = ld4(Aptr + (tile+1)*16);
            bR = ld4(Bptr + (size_t)(tile+1)*16*512);
        }
#pragma unroll
        for (int k = 0; k < 16; ++k) {
            float4 ra = *reinterpret_cast<const float4*>(&As[k][ty*4]);
            float4 rb = *reinterpret_cast<const float4*>(&Bs[k][tx*4]);
            const float av[4] = {ra.x, ra.y, ra.z, ra.w};
            const float bv[4] = {rb.x, rb.y, rb.z, rb.w};
#pragma unroll
            for (int i = 0; i < 4; ++i)
#pragma unroll
                for (int j = 0; j < 4; ++j)
                    acc[i][j] = fmaf(av[i], bv[j], acc[i][j]);
        }
        __syncthreads();
    }
#pragma unroll
    for (int i = 0; i < 4; ++i) {
        float4 v = make_float4(acc[i][0], acc[i][1], acc[i][2], acc[i][3]);
        *reinterpret_cast<float4*>(&P[((size_t)ks*NB + bm + ty*4 + i) * NTOT + bn + tx*4]) = v;
    }
}

// ================================================================
// Reduce gemm1 partials -> C1 (+bias per 512-col group). 512 blocks x 256.
// ================================================================
__global__ __launch_bounds__(256) void k_red1(
    const float* __restrict__ P,
    const float* __restrict__ b0, const float* __restrict__ b1,
    const float* __restrict__ b2, const float* __restrict__ b3,
    float* __restrict__ C1)
{
    const size_t q = ((size_t)blockIdx.x * 256 + threadIdx.x) * 4;  // < 256*2048
    const int c = (int)(q & 2047);
    float4 s0 = ld4(P + q);
    float4 s1 = ld4(P + 524288 + q);
    float4 s2 = ld4(P + 2*524288 + q);
    float4 s3 = ld4(P + 3*524288 + q);
    const int mat = c >> 9, cl = c & 511;
    const float* bb = (mat == 0) ? b0 : (mat == 1) ? b1 : (mat == 2) ? b2 : b3;
    float4 o;
    o.x = s0.x + s1.x + s2.x + s3.x + bb[cl+0];
    o.y = s0.y + s1.y + s2.y + s3.y + bb[cl+1];
    o.z = s0.z + s1.z + s2.z + s3.z + bb[cl+2];
    o.w = s0.w + s1.w + s2.w + s3.w + bb[cl+3];
    *reinterpret_cast<float4*>(&C1[q]) = o;
}

// ================================================================
// Kernel 3: first pass over kb (Find/Scene attn + katt partial sums)
// ================================================================
__global__ __launch_bounds__(256) void k_kbA(
    const float* __restrict__ kb, const float* __restrict__ C1,
    const float* __restrict__ w_find, const float* __restrict__ b_find,
    const float* __restrict__ w_scene, const float* __restrict__ b_scene,
    const float* __restrict__ w1g, const float* __restrict__ w2g,
    float* __restrict__ aF, float* __restrict__ aS, float* __restrict__ kpart)
{
    const int blk = blockIdx.x;
    const int n = blk >> 2, sp = blk & 3;
    const int t = threadIdx.x, wv = t >> 6, lane = t & 63;
    const int k0 = lane * 8;
    const int p0 = sp * 49;

    __shared__ float w1s[49], w2s[49];
    __shared__ float kred[4][1024];
    if (t < 49) { w1s[t] = w1g[n*HW + p0 + t]; w2s[t] = w2g[n*HW + p0 + t]; }
    __syncthreads();

    float cf[8], wf[8], wsc[8];
    {
        float4 a0 = ld4(C1 + (size_t)n*2048 + k0), a1 = ld4(C1 + (size_t)n*2048 + k0 + 4);
        cf[0]=a0.x; cf[1]=a0.y; cf[2]=a0.z; cf[3]=a0.w; cf[4]=a1.x; cf[5]=a1.y; cf[6]=a1.z; cf[7]=a1.w;
        float4 b0 = ld4(w_find + k0), b1 = ld4(w_find + k0 + 4);
        wf[0]=b0.x; wf[1]=b0.y; wf[2]=b0.z; wf[3]=b0.w; wf[4]=b1.x; wf[5]=b1.y; wf[6]=b1.z; wf[7]=b1.w;
        float4 c0 = ld4(w_scene + k0), c1 = ld4(w_scene + k0 + 4);
        wsc[0]=c0.x; wsc[1]=c0.y; wsc[2]=c0.z; wsc[3]=c0.w; wsc[4]=c1.x; wsc[5]=c1.y; wsc[6]=c1.z; wsc[7]=c1.w;
    }
    const float bf = b_find[0], bs = b_scene[0];

    float k1a[8] = {0,0,0,0,0,0,0,0};
    float k2a[8] = {0,0,0,0,0,0,0,0};

    for (int pl = wv; pl < 49; pl += 4) {
        const float* src = kb + (((size_t)n*HW + p0 + pl) * KBC + k0);
        float4 v0 = ld4(src), v1 = ld4(src + 4);
        float kv[8] = {v0.x, v0.y, v0.z, v0.w, v1.x, v1.y, v1.z, v1.w};
        float sA = 0.f, sB = 0.f, sE = 0.f, sF = 0.f;
#pragma unroll
        for (int j = 0; j < 8; ++j) {
            const float t1 = kv[j] * cf[j];
            sA = fmaf(t1, t1, sA);
            sB = fmaf(t1, wf[j], sB);
            sE = fmaf(kv[j], kv[j], sE);
            sF = fmaf(kv[j], wsc[j], sF);
        }
        const float w1p = w1s[pl], w2p = w2s[pl];
#pragma unroll
        for (int j = 0; j < 8; ++j) {
            k1a[j] = fmaf(w1p, kv[j], k1a[j]);
            k2a[j] = fmaf(w2p, kv[j], k2a[j]);
        }
#pragma unroll
        for (int m = 1; m < 64; m <<= 1) {
            sA += __shfl_xor(sA, m);
            sB += __shfl_xor(sB, m);
            sE += __shfl_xor(sE, m);
            sF += __shfl_xor(sF, m);
        }
        if (lane == 0) {
            const size_t p = (size_t)n*HW + p0 + pl;
            aF[p] = sB / fmaxf(sqrtf(sA), EPSF) + bf;
            aS[p] = sF / fmaxf(sqrtf(sE), EPSF) + bs;
        }
    }
#pragma unroll
    for (int j = 0; j < 8; ++j) { kred[wv][k0 + j] = k1a[j]; kred[wv][512 + k0 + j] = k2a[j]; }
    __syncthreads();
    for (int idx = t; idx < 1024; idx += 256) {
        const float s = kred[0][idx] + kred[1][idx] + kred[2][idx] + kred[3][idx];
        kpart[((size_t)sp*NB + n) * 1024 + idx] = s;
    }
}

// ================================================================
// Kernel 4: reduce katt partials; g = c_tr*katt2; l2norm elts;
// A1' = p7*[ctrl|elt1|katt2], A2' = p8*[ctrl|elt2|katt1]  (prob folded in).
// ================================================================
__global__ __launch_bounds__(256) void k_elt(
    const float* __restrict__ kpart, const float* __restrict__ C1,
    const float* __restrict__ control, const float* __restrict__ prob,
    float* __restrict__ g, float* __restrict__ A1, float* __restrict__ A2)
{
    const int n = blockIdx.x;
    const int t = threadIdx.x;
    __shared__ float k1s[512], k2s[512];
    for (int idx = t; idx < 512; idx += 256) {
        float s1 = 0.f, s2 = 0.f;
#pragma unroll
        for (int sp = 0; sp < 4; ++sp) {
            const float* base = kpart + ((size_t)sp*NB + n) * 1024;
            s1 += base[idx];
            s2 += base[512 + idx];
        }
        k1s[idx] = s1; k2s[idx] = s2;
    }
    __syncthreads();

    float v1[2], v2[2];
    float sum1 = 0.f, sum2 = 0.f;
#pragma unroll
    for (int i = 0; i < 2; ++i) {
        const int k = t + i*256;
        const float ct  = C1[(size_t)n*2048 + 512  + k];
        const float cd1 = C1[(size_t)n*2048 + 1024 + k];
        const float cd2 = C1[(size_t)n*2048 + 1536 + k];
        g[(size_t)n*512 + k] = ct * k2s[k];
        v1[i] = cd1 * k2s[k];
        v2[i] = cd2 * k1s[k] * k2s[k];
        sum1 = fmaf(v1[i], v1[i], sum1);
        sum2 = fmaf(v2[i], v2[i], sum2);
    }
    __shared__ float r1[256], r2[256];
    r1[t] = sum1; r2[t] = sum2;
    __syncthreads();
    for (int off = 128; off > 0; off >>= 1) {
        if (t < off) { r1[t] += r1[t+off]; r2[t] += r2[t+off]; }
        __syncthreads();
    }
    const float n1 = fmaxf(sqrtf(r1[0]), EPSF);
    const float n2 = fmaxf(sqrtf(r2[0]), EPSF);
    const float p7 = prob[n*9 + 7], p8 = prob[n*9 + 8];
#pragma unroll
    for (int i = 0; i < 2; ++i) {
        const int k = t + i*256;
        const float c = control[(size_t)n*512 + k];
        A1[(size_t)n*1536 + k]        = p7 * c;
        A1[(size_t)n*1536 + 512 + k]  = p7 * v1[i] / n1;
        A1[(size_t)n*1536 + 1024 + k] = p7 * k2s[k];
        A2[(size_t)n*1536 + k]        = p8 * c;
        A2[(size_t)n*1536 + 512 + k]  = p8 * v2[i] / n2;
        A2[(size_t)n*1536 + 1024 + k] = p8 * k1s[k];
    }
}

// ================================================================
// Kernel 5: second pass over kb — Transform attention.
// ================================================================
__global__ __launch_bounds__(256) void k_kbB(
    const float* __restrict__ kb, const float* __restrict__ g,
    const float* __restrict__ w_tr, const float* __restrict__ b_tr,
    float* __restrict__ aT)
{
    const int blk = blockIdx.x;
    const int n = blk >> 2, sp = blk & 3;
    const int t = threadIdx.x, wv = t >> 6, lane = t & 63;
    const int k0 = lane * 8;
    const int p0 = sp * 49;
    float gv[8], wt[8];
    {
        float4 a0 = ld4(g + (size_t)n*512 + k0), a1 = ld4(g + (size_t)n*512 + k0 + 4);
        gv[0]=a0.x; gv[1]=a0.y; gv[2]=a0.z; gv[3]=a0.w; gv[4]=a1.x; gv[5]=a1.y; gv[6]=a1.z; gv[7]=a1.w;
        float4 b0 = ld4(w_tr + k0), b1 = ld4(w_tr + k0 + 4);
        wt[0]=b0.x; wt[1]=b0.y; wt[2]=b0.z; wt[3]=b0.w; wt[4]=b1.x; wt[5]=b1.y; wt[6]=b1.z; wt[7]=b1.w;
    }
    const float bt = b_tr[0];
    for (int pl = wv; pl < 49; pl += 4) {
        const float* src = kb + (((size_t)n*HW + p0 + pl) * KBC + k0);
        float4 v0 = ld4(src), v1 = ld4(src + 4);
        float kv[8] = {v0.x, v0.y, v0.z, v0.w, v1.x, v1.y, v1.z, v1.w};
        float sC = 0.f, sD = 0.f;
#pragma unroll
        for (int j = 0; j < 8; ++j) {
            const float u = kv[j] * gv[j];
            sC = fmaf(u, u, sC);
            sD = fmaf(u, wt[j], sD);
        }
#pragma unroll
        for (int m = 1; m < 64; m <<= 1) { sC += __shfl_xor(sC, m); sD += __shfl_xor(sD, m); }
        if (lane == 0) aT[(size_t)n*HW + p0 + pl] = sD / fmaxf(sqrtf(sC), EPSF) + bt;
    }
}

// ================================================================
// Kernel 7: out_mem = p0*mem_prev + sum_s P2[s] + p7*b1 + p8*b2
// (P2 holds the fused, prob-pre-scaled mem GEMM partials.) 128 blocks x 256.
// ================================================================
__global__ __launch_bounds__(256) void k_memout(
    const float* __restrict__ P2, const float* __restrict__ memprev,
    const float* __restrict__ prob,
    const float* __restrict__ b1, const float* __restrict__ b2,
    float* __restrict__ out_mem)
{
    const size_t q = ((size_t)blockIdx.x * 256 + threadIdx.x) * 4;  // < 256*512
    const int n = (int)(q >> 9), j = (int)(q & 511);
    const float p0 = prob[n*9 + 0], p7 = prob[n*9 + 7], p8 = prob[n*9 + 8];
    float4 s = ld4(P2 + q);
#pragma unroll
    for (int sp = 1; sp < 8; ++sp) {
        float4 v = ld4(P2 + (size_t)sp*131072 + q);
        s.x += v.x; s.y += v.y; s.z += v.z; s.w += v.w;
    }
    float4 mp = ld4(memprev + q);
    float4 w1 = ld4(b1 + j), w2 = ld4(b2 + j);
    float4 o;
    o.x = p0*mp.x + s.x + p7*w1.x + p8*w2.x;
    o.y = p0*mp.y + s.y + p7*w1.y + p8*w2.y;
    o.z = p0*mp.z + s.z + p7*w1.z + p8*w2.z;
    o.w = p0*mp.w + s.w + p7*w1.w + p8*w2.w;
    *reinterpret_cast<float4*>(&out_mem[q]) = o;
}

// ================================================================
// Kernel 8: assemble att_stack_avg + stack_ptr_avg.
// ================================================================
__global__ __launch_bounds__(256) void k_assemble(
    const float* __restrict__ stk, const float* __restrict__ ptrp,
    const float* __restrict__ prob,
    const float* __restrict__ att1g, const float* __restrict__ att2g,
    const float* __restrict__ aFg, const float* __restrict__ aTg, const float* __restrict__ aSg,
    const float* __restrict__ fws, const float* __restrict__ bws, const float* __restrict__ fbws,
    const float* __restrict__ sf2ws, const float* __restrict__ sffbws,
    float* __restrict__ out_att, float* __restrict__ out_ptr)
{
    const int n = blockIdx.x;
    const int t = threadIdx.x;
    __shared__ float pp[8], f[8], b[8], fb[8], pr[9], sc2[2];
    if (t < 8) { pp[t] = ptrp[n*8+t]; f[t] = fws[n*8+t]; b[t] = bws[n*8+t]; fb[t] = fbws[n*8+t]; }
    if (t < 9) pr[t] = prob[n*9+t];
    if (t == 0) { sc2[0] = sf2ws[n]; sc2[1] = sffbws[n]; }
    __syncthreads();

    if (t < HW) {
        const size_t p = (size_t)n*HW + t;
        const float* spt = stk + p*8;
        float4 v0 = ld4(spt), v1 = ld4(spt+4);
        float s[8] = {v0.x, v0.y, v0.z, v0.w, v1.x, v1.y, v1.z, v1.w};
        const float a1 = att1g[p], a2 = att2g[p];
        const float vaF = aFg[p], vaT = aTg[p], vaS = aSg[p];
        const float mn = fminf(a1, a2), mx = fmaxf(a1, a2);
        float rf = 0.f, rf2 = 0.f, rfb = 0.f, rffb = 0.f;
#pragma unroll
        for (int l = 0; l < 8; ++l) {
            rf   = fmaf(s[l], f[l],        rf);
            rf2  = fmaf(s[l], f[l]*f[l],   rf2);
            rfb  = fmaf(s[l], fb[l],       rfb);
            rffb = fmaf(s[l], f[l]*fb[l],  rffb);
        }
        const float att2p = vaF*sc2[0] + rf  - rf2;
        const float att1p = vaF*sc2[1] + rfb - rffb;
        const float mnF = fminf(att1p, att2p);
        const float c48 = pr[4] + pr[8];
        float o[8];
#pragma unroll
        for (int l = 0; l < 8; ++l) {
            const float sl = s[l];
            const float stkF = vaF*f[l] + sl*(1.f - f[l]);
            float r = (pr[0] + pr[7]) * sl;
            r = fmaf(pr[1], stkF, r);
            r = fmaf(pr[2], vaT*pp[l] + sl*(1.f - pp[l]), r);
            r = fmaf(pr[3], mnF*fb[l] + stkF*(1.f - fb[l]), r);
            r = fmaf(c48,   mn*b[l] + sl*(1.f - b[l]), r);
            r = fmaf(pr[5], mx*b[l] + sl*(1.f - b[l]), r);
            r = fmaf(pr[6], vaS*f[l] + sl*(1.f - f[l]), r);
            o[l] = r;
        }
        *reinterpret_cast<float4*>(out_att + p*8)     = make_float4(o[0], o[1], o[2], o[3]);
        *reinterpret_cast<float4*>(out_att + p*8 + 4) = make_float4(o[4], o[5], o[6], o[7]);
    }

    if (t == 0) {
        const float cpp = pr[0] + pr[2] + pr[7];
        const float cf  = pr[1] + pr[6];
        const float cb  = pr[4] + pr[5] + pr[8];
        float pa[8];
        float m = -3.0e38f;
#pragma unroll
        for (int l = 0; l < 8; ++l) {
            pa[l] = cpp*pp[l] + cf*f[l] + cb*b[l] + pr[3]*fb[l];
            m = fmaxf(m, pa[l]);
        }
        float ssum = 0.f;
#pragma unroll
        for (int l = 0; l < 8; ++l) { pa[l] = __expf(pa[l] - m); ssum += pa[l]; }
#pragma unroll
        for (int l = 0; l < 8; ++l) out_ptr[n*8 + l] = pa[l] / ssum;
    }
}

// ================================================================
extern "C" void kernel_launch(void* const* d_in, const int* in_sizes, int n_in,
                              void* d_out, int out_size, void* d_ws, size_t ws_size,
                              hipStream_t stream)
{
    (void)in_sizes; (void)n_in; (void)out_size;
    const float* control = (const float*)d_in[0];
    const float* kb      = (const float*)d_in[1];
    const float* prob    = (const float*)d_in[2];
    const float* memprev = (const float*)d_in[3];
    const float* stk     = (const float*)d_in[4];
    const float* ptrp    = (const float*)d_in[5];
    const float* find_w  = (const float*)d_in[6];
    const float* find_b  = (const float*)d_in[7];
    const float* findc_w = (const float*)d_in[8];
    const float* findc_b = (const float*)d_in[9];
    const float* tr_w    = (const float*)d_in[10];
    const float* tr_b    = (const float*)d_in[11];
    const float* trc_w   = (const float*)d_in[12];
    const float* trc_b   = (const float*)d_in[13];
    const float* sc_w    = (const float*)d_in[14];
    const float* sc_b    = (const float*)d_in[15];
    const float* d1_w    = (const float*)d_in[16];
    const float* d1_b    = (const float*)d_in[17];
    const float* d1m_w   = (const float*)d_in[18];
    const float* d1m_b   = (const float*)d_in[19];
    const float* d2_w    = (const float*)d_in[20];
    const float* d2_b    = (const float*)d_in[21];
    const float* d2m_w   = (const float*)d_in[22];
    const float* d2m_b   = (const float*)d_in[23];

    if (ws_size < WS_FLOATS * sizeof(float)) return;

    float* ws    = (float*)d_ws;
    float* att1g = ws + OFF_ATT1;
    float* att2g = ws + OFF_ATT2;
    float* w1g   = ws + OFF_W1;
    float* w2g   = ws + OFF_W2;
    float* aF    = ws + OFF_AF;
    float* aT    = ws + OFF_AT;
    float* aS    = ws + OFF_AS;
    float* C1    = ws + OFF_C1;
    float* A1    = ws + OFF_A1;
    float* A2    = ws + OFF_A2;
    float* g     = ws + OFF_G;
    float* scr   = ws + OFF_SCR;     // kpart, then gemm2 partials
    float* GP1   = ws + OFF_A1;      // gemm1 partials [4][256][2048] (pre-A1/A2/G)
    float* fws   = ws + OFF_PF;
    float* bws   = ws + OFF_PB;
    float* fbws  = ws + OFF_PFB;
    float* sf2   = ws + OFF_SF2;
    float* sffb  = ws + OFF_SFFB;

    float* out_att = (float*)d_out;
    float* out_ptr = out_att + (size_t)NB*HW*LSZ;
    float* out_mem = out_ptr + (size_t)NB*LSZ;

    // 1. stack reads + softmax weights + ptr variants
    k_att<<<NB, 256, 0, stream>>>(stk, ptrp, att1g, att2g, w1g, w2g,
                                  fws, bws, fbws, sf2, sffb);
    // 2. C1 = control @ [find|transform|d1|d2]_ci : split-K partials, then reduce
    gemm_sk<128, false, 512, 2048><<<dim3(32, 4, 4), 256, 0, stream>>>(
        control, nullptr, find_w, tr_w, d1_w, d2_w, GP1);
    k_red1<<<512, 256, 0, stream>>>(GP1, find_b, tr_b, d1_b, d2_b, C1);
    // 3. kb pass A
    k_kbA<<<NB*4, 256, 0, stream>>>(kb, C1, findc_w, findc_b, sc_w, sc_b,
                                    w1g, w2g, aF, aS, scr);
    // 4. katt reduce, g, elts, prob-scaled concat matrices
    k_elt<<<NB, 256, 0, stream>>>(scr, C1, control, prob, g, A1, A2);
    // 5. kb pass B
    k_kbB<<<NB*4, 256, 0, stream>>>(kb, g, trc_w, trc_b, aT);
    // 6. fused mem GEMM: [p7*A1 | p8*A2] @ vstack(d1m_w, d2m_w), split-K=8
    gemm_sk<384, true, 1536, 512><<<dim3(8, 4, 8), 256, 0, stream>>>(
        A1, A2, d1m_w, d2m_w, nullptr, nullptr, scr);
    // 7. mem_avg (reduces gemm2 partials + biases + mem_prev)
    k_memout<<<128, 256, 0, stream>>>(scr, memprev, prob, d1m_b, d2m_b, out_mem);
    // 8. att_stack_avg + stack_ptr_avg
    k_assemble<<<NB, 256, 0, stream>>>(stk, ptrp, prob, att1g, att2g, aF, aT, aS,
                                       fws, bws, fbws, sf2, sffb, out_att, out_ptr);
}

// Round 3
// 78.380 us; speedup vs baseline: 1.9459x; 1.1808x over previous
//
#include <hip/hip_runtime.h>
#include <math.h>

// Problem constants: N=256, H*W=196, KB=512, CTRL=512, MEM=512, L=8, NMOD=9. f32.
constexpr int   NB   = 256;
constexpr int   HW   = 196;
constexpr int   KBC  = 512;
constexpr int   LSZ  = 8;
constexpr float EPSF = 1e-12f;

// ---------------- workspace layout (floats), no aliasing (ws ~392 MB) ------
constexpr size_t S_ATT    = (size_t)NB * HW;                  // 50176
constexpr size_t OFF_ATT1 = 0;
constexpr size_t OFF_ATT2 = OFF_ATT1 + S_ATT;
constexpr size_t OFF_W1   = OFF_ATT2 + S_ATT;
constexpr size_t OFF_W2   = OFF_W1   + S_ATT;
constexpr size_t OFF_AF   = OFF_W2   + S_ATT;
constexpr size_t OFF_AT   = OFF_AF   + S_ATT;
constexpr size_t OFF_AS   = OFF_AT   + S_ATT;
constexpr size_t OFF_GP1  = OFF_AS   + S_ATT;                 // [4][256][2048] gemm1 partials
constexpr size_t OFF_KP   = OFF_GP1  + (size_t)4*NB*2048;     // [4][256][1024] katt partials
constexpr size_t OFF_A1   = OFF_KP   + (size_t)4*NB*1024;     // 256 x 1536
constexpr size_t OFF_A2   = OFF_A1   + (size_t)NB*1536;       // 256 x 1536
constexpr size_t OFF_G    = OFF_A2   + (size_t)NB*1536;       // 256 x 512
constexpr size_t OFF_P2   = OFF_G    + (size_t)NB*512;        // [16][256][512] gemm2 partials
constexpr size_t OFF_PF   = OFF_P2   + (size_t)16*NB*512;
constexpr size_t OFF_PB   = OFF_PF   + (size_t)NB*LSZ;
constexpr size_t OFF_PFB  = OFF_PB   + (size_t)NB*LSZ;
constexpr size_t OFF_SF2  = OFF_PFB  + (size_t)NB*LSZ;
constexpr size_t OFF_SFFB = OFF_SF2  + NB;
constexpr size_t WS_FLOATS= OFF_SFFB + NB;                    // ~6.5M floats = 26 MB

static __device__ __forceinline__ float4 ld4(const float* p) {
    return *reinterpret_cast<const float4*>(p);
}

// ================================================================
// k_front: blocks 0..255 -> k_att (per-n ptr variants, stack reads, softmax)
//          blocks 256..767 -> gemm1 split-K partials
//             GP1[ks][256][2048] = control @ [find|tr|d1|d2]_ci (no bias)
// ================================================================
__global__ __launch_bounds__(256) void k_front(
    const float* __restrict__ stk, const float* __restrict__ ptrp,
    float* __restrict__ att1g, float* __restrict__ att2g,
    float* __restrict__ w1g, float* __restrict__ w2g,
    float* __restrict__ fws, float* __restrict__ bws, float* __restrict__ fbws,
    float* __restrict__ sf2ws, float* __restrict__ sffbws,
    const float* __restrict__ control,
    const float* __restrict__ B0, const float* __restrict__ B1,
    const float* __restrict__ B2, const float* __restrict__ B3,
    float* __restrict__ GP1)
{
    __shared__ float red[256];
    __shared__ float As[16][68];
    __shared__ float Bs[16][68];
    const int t = threadIdx.x;

    if (blockIdx.x < 256) {
        const int n = blockIdx.x;
        float pp[8], f[8], b[8], fb[8];
#pragma unroll
        for (int l = 0; l < 8; ++l) pp[l] = ptrp[n*8 + l];
        f[0] = 0.f;
#pragma unroll
        for (int l = 1; l < 8; ++l) f[l] = pp[l-1];
        f[7] += pp[7];
#pragma unroll
        for (int l = 0; l < 7; ++l) b[l] = pp[l+1];
        b[7] = 0.f;
        b[0] += pp[0];
#pragma unroll
        for (int l = 0; l < 7; ++l) fb[l] = f[l+1];
        fb[7] = 0.f;
        fb[0] += f[0];

        if (t == 0) {
            float sf2 = 0.f, sffb = 0.f;
#pragma unroll
            for (int l = 0; l < 8; ++l) {
                fws[n*8+l] = f[l]; bws[n*8+l] = b[l]; fbws[n*8+l] = fb[l];
                sf2  += f[l]*f[l];
                sffb += f[l]*fb[l];
            }
            sf2ws[n] = sf2; sffbws[n] = sffb;
        }

        float a1 = 0.f, a2 = 0.f;
        if (t < HW) {
            const float* sp = stk + ((size_t)n*HW + t) * 8;
            float4 v0 = ld4(sp), v1 = ld4(sp + 4);
            float s[8] = {v0.x, v0.y, v0.z, v0.w, v1.x, v1.y, v1.z, v1.w};
#pragma unroll
            for (int l = 0; l < 8; ++l) {
                a2 = fmaf(s[l], pp[l], a2);
                a1 = fmaf(s[l],  b[l], a1);
            }
            att1g[n*HW + t] = a1;
            att2g[n*HW + t] = a2;
        }

        red[t] = (t < HW) ? a1 : -3.0e38f;
        __syncthreads();
        for (int off = 128; off > 0; off >>= 1) { if (t < off) red[t] = fmaxf(red[t], red[t+off]); __syncthreads(); }
        const float m1 = red[0];
        __syncthreads();
        float e1 = (t < HW) ? __expf(a1 - m1) : 0.f;
        red[t] = e1;
        __syncthreads();
        for (int off = 128; off > 0; off >>= 1) { if (t < off) red[t] += red[t+off]; __syncthreads(); }
        const float s1 = red[0];
        __syncthreads();
        if (t < HW) w1g[n*HW + t] = e1 / s1;

        red[t] = (t < HW) ? a2 : -3.0e38f;
        __syncthreads();
        for (int off = 128; off > 0; off >>= 1) { if (t < off) red[t] = fmaxf(red[t], red[t+off]); __syncthreads(); }
        const float m2 = red[0];
        __syncthreads();
        float e2 = (t < HW) ? __expf(a2 - m2) : 0.f;
        red[t] = e2;
        __syncthreads();
        for (int off = 128; off > 0; off >>= 1) { if (t < off) red[t] += red[t+off]; __syncthreads(); }
        const float s2 = red[0];
        __syncthreads();
        if (t < HW) w2g[n*HW + t] = e2 / s2;
        return;
    }

    // ---- gemm1: BM=BN=64, BK=16, TM=TN=4, KCHUNK=128 ----
    const int idx = blockIdx.x - 256;            // 0..511
    const int bn = (idx & 31) * 64;              // 2048/64 = 32 col tiles
    const int bm = ((idx >> 5) & 3) * 64;        // 256/64 = 4 row tiles
    const int ks = idx >> 7;                     // 4 K splits
    const int mat = bn >> 9;
    const float* B = (mat == 0) ? B0 : (mat == 1) ? B1 : (mat == 2) ? B2 : B3;
    const int kbase = ks * 128;
    const int bcol = bn & 511;

    const int tx = t & 15, ty = t >> 4;
    float acc[4][4] = {};
    const int ar = t >> 2, ac4 = (t & 3) * 4;
    const int br = t >> 4, bc4 = (t & 15) * 4;
    const float* Aptr = control + (size_t)(bm + ar) * 512 + kbase + ac4;
    const float* Bptr = B + (size_t)(kbase + br) * 512 + bcol + bc4;

    float4 aR = ld4(Aptr), bR = ld4(Bptr);
    for (int tile = 0; tile < 8; ++tile) {
        As[ac4+0][ar] = aR.x; As[ac4+1][ar] = aR.y; As[ac4+2][ar] = aR.z; As[ac4+3][ar] = aR.w;
        *reinterpret_cast<float4*>(&Bs[br][bc4]) = bR;
        __syncthreads();
        if (tile + 1 < 8) {
            aR = ld4(Aptr + (tile+1)*16);
            bR = ld4(Bptr + (size_t)(tile+1)*16*512);
        }
#pragma unroll
        for (int k = 0; k < 16; ++k) {
            float4 ra = *reinterpret_cast<const float4*>(&As[k][ty*4]);
            float4 rb = *reinterpret_cast<const float4*>(&Bs[k][tx*4]);
            const float av[4] = {ra.x, ra.y, ra.z, ra.w};
            const float bv[4] = {rb.x, rb.y, rb.z, rb.w};
#pragma unroll
            for (int i = 0; i < 4; ++i)
#pragma unroll
                for (int j = 0; j < 4; ++j)
                    acc[i][j] = fmaf(av[i], bv[j], acc[i][j]);
        }
        __syncthreads();
    }
#pragma unroll
    for (int i = 0; i < 4; ++i) {
        float4 v = make_float4(acc[i][0], acc[i][1], acc[i][2], acc[i][3]);
        *reinterpret_cast<float4*>(&GP1[((size_t)ks*NB + bm + ty*4 + i) * 2048 + bn + tx*4]) = v;
    }
}

// ================================================================
// k_kbA: first pass over kb. c_find reduced in-kernel from GP1 + bias.
// grid = 1024 (4 pixel-splits per n), 256 threads.
// ================================================================
__global__ __launch_bounds__(256) void k_kbA(
    const float* __restrict__ kb, const float* __restrict__ GP1,
    const float* __restrict__ find_ci_b,
    const float* __restrict__ w_find, const float* __restrict__ b_find,
    const float* __restrict__ w_scene, const float* __restrict__ b_scene,
    const float* __restrict__ w1g, const float* __restrict__ w2g,
    float* __restrict__ aF, float* __restrict__ aS, float* __restrict__ kpart)
{
    const int blk = blockIdx.x;
    const int n = blk >> 2, sp = blk & 3;
    const int t = threadIdx.x, wv = t >> 6, lane = t & 63;
    const int k0 = lane * 8;
    const int p0 = sp * 49;

    __shared__ float w1s[49], w2s[49];
    __shared__ float kred[4][1024];
    if (t < 49) { w1s[t] = w1g[n*HW + p0 + t]; w2s[t] = w2g[n*HW + p0 + t]; }
    __syncthreads();

    float cf[8], wf[8], wsc[8];
    {
        const float* gp = GP1 + (size_t)n*2048 + k0;
        float4 a0 = ld4(gp),            a1 = ld4(gp + 4);
        float4 b0 = ld4(gp + 524288),   b1 = ld4(gp + 524288 + 4);
        float4 c0 = ld4(gp + 1048576),  c1 = ld4(gp + 1048576 + 4);
        float4 d0 = ld4(gp + 1572864),  d1 = ld4(gp + 1572864 + 4);
        float4 e0 = ld4(find_ci_b + k0), e1 = ld4(find_ci_b + k0 + 4);
        cf[0]=a0.x+b0.x+c0.x+d0.x+e0.x; cf[1]=a0.y+b0.y+c0.y+d0.y+e0.y;
        cf[2]=a0.z+b0.z+c0.z+d0.z+e0.z; cf[3]=a0.w+b0.w+c0.w+d0.w+e0.w;
        cf[4]=a1.x+b1.x+c1.x+d1.x+e1.x; cf[5]=a1.y+b1.y+c1.y+d1.y+e1.y;
        cf[6]=a1.z+b1.z+c1.z+d1.z+e1.z; cf[7]=a1.w+b1.w+c1.w+d1.w+e1.w;
        float4 f0 = ld4(w_find + k0), f1 = ld4(w_find + k0 + 4);
        wf[0]=f0.x; wf[1]=f0.y; wf[2]=f0.z; wf[3]=f0.w; wf[4]=f1.x; wf[5]=f1.y; wf[6]=f1.z; wf[7]=f1.w;
        float4 g0 = ld4(w_scene + k0), g1 = ld4(w_scene + k0 + 4);
        wsc[0]=g0.x; wsc[1]=g0.y; wsc[2]=g0.z; wsc[3]=g0.w; wsc[4]=g1.x; wsc[5]=g1.y; wsc[6]=g1.z; wsc[7]=g1.w;
    }
    const float bf = b_find[0], bs = b_scene[0];

    float k1a[8] = {0,0,0,0,0,0,0,0};
    float k2a[8] = {0,0,0,0,0,0,0,0};

    const float* src0 = kb + (((size_t)n*HW + p0 + wv) * KBC + k0);
    float4 v0 = ld4(src0), v1 = ld4(src0 + 4);
    for (int pl = wv; pl < 49; pl += 4) {
        float4 n0, n1;
        if (pl + 4 < 49) {
            const float* ns = kb + (((size_t)n*HW + p0 + pl + 4) * KBC + k0);
            n0 = ld4(ns); n1 = ld4(ns + 4);
        }
        float kv[8] = {v0.x, v0.y, v0.z, v0.w, v1.x, v1.y, v1.z, v1.w};
        float sA = 0.f, sB = 0.f, sE = 0.f, sF = 0.f;
#pragma unroll
        for (int j = 0; j < 8; ++j) {
            const float t1 = kv[j] * cf[j];
            sA = fmaf(t1, t1, sA);
            sB = fmaf(t1, wf[j], sB);
            sE = fmaf(kv[j], kv[j], sE);
            sF = fmaf(kv[j], wsc[j], sF);
        }
        const float w1p = w1s[pl], w2p = w2s[pl];
#pragma unroll
        for (int j = 0; j < 8; ++j) {
            k1a[j] = fmaf(w1p, kv[j], k1a[j]);
            k2a[j] = fmaf(w2p, kv[j], k2a[j]);
        }
#pragma unroll
        for (int m = 1; m < 64; m <<= 1) {
            sA += __shfl_xor(sA, m);
            sB += __shfl_xor(sB, m);
            sE += __shfl_xor(sE, m);
            sF += __shfl_xor(sF, m);
        }
        if (lane == 0) {
            const size_t p = (size_t)n*HW + p0 + pl;
            aF[p] = sB / fmaxf(sqrtf(sA), EPSF) + bf;
            aS[p] = sF / fmaxf(sqrtf(sE), EPSF) + bs;
        }
        v0 = n0; v1 = n1;
    }
#pragma unroll
    for (int j = 0; j < 8; ++j) { kred[wv][k0 + j] = k1a[j]; kred[wv][512 + k0 + j] = k2a[j]; }
    __syncthreads();
    for (int idx = t; idx < 1024; idx += 256) {
        const float s = kred[0][idx] + kred[1][idx] + kred[2][idx] + kred[3][idx];
        kpart[((size_t)sp*NB + n) * 1024 + idx] = s;
    }
}

// ================================================================
// k_elt: reduce katt partials; reduce GP1 for c_tr/c_d1/c_d2 (+biases);
// g = c_tr*katt2; l2norm elts; A1' = p7*[ctrl|elt1|katt2], A2' = p8*[...].
// ================================================================
__global__ __launch_bounds__(256) void k_elt(
    const float* __restrict__ kpart, const float* __restrict__ GP1,
    const float* __restrict__ tr_ci_b, const float* __restrict__ d1_ci_b,
    const float* __restrict__ d2_ci_b,
    const float* __restrict__ control, const float* __restrict__ prob,
    float* __restrict__ g, float* __restrict__ A1, float* __restrict__ A2)
{
    const int n = blockIdx.x;
    const int t = threadIdx.x;
    __shared__ float k1s[512], k2s[512];
    for (int idx = t; idx < 512; idx += 256) {
        float s1 = 0.f, s2 = 0.f;
#pragma unroll
        for (int sp = 0; sp < 4; ++sp) {
            const float* base = kpart + ((size_t)sp*NB + n) * 1024;
            s1 += base[idx];
            s2 += base[512 + idx];
        }
        k1s[idx] = s1; k2s[idx] = s2;
    }
    __syncthreads();

    float v1[2], v2[2];
    float sum1 = 0.f, sum2 = 0.f;
#pragma unroll
    for (int i = 0; i < 2; ++i) {
        const int k = t + i*256;
        const float* gp = GP1 + (size_t)n*2048 + k;
        const float ct  = gp[512]  + gp[524288+512]  + gp[1048576+512]  + gp[1572864+512]  + tr_ci_b[k];
        const float cd1 = gp[1024] + gp[524288+1024] + gp[1048576+1024] + gp[1572864+1024] + d1_ci_b[k];
        const float cd2 = gp[1536] + gp[524288+1536] + gp[1048576+1536] + gp[1572864+1536] + d2_ci_b[k];
        g[(size_t)n*512 + k] = ct * k2s[k];
        v1[i] = cd1 * k2s[k];
        v2[i] = cd2 * k1s[k] * k2s[k];
        sum1 = fmaf(v1[i], v1[i], sum1);
        sum2 = fmaf(v2[i], v2[i], sum2);
    }
    __shared__ float r1[256], r2[256];
    r1[t] = sum1; r2[t] = sum2;
    __syncthreads();
    for (int off = 128; off > 0; off >>= 1) {
        if (t < off) { r1[t] += r1[t+off]; r2[t] += r2[t+off]; }
        __syncthreads();
    }
    const float n1 = fmaxf(sqrtf(r1[0]), EPSF);
    const float n2 = fmaxf(sqrtf(r2[0]), EPSF);
    const float p7 = prob[n*9 + 7], p8 = prob[n*9 + 8];
#pragma unroll
    for (int i = 0; i < 2; ++i) {
        const int k = t + i*256;
        const float c = control[(size_t)n*512 + k];
        A1[(size_t)n*1536 + k]        = p7 * c;
        A1[(size_t)n*1536 + 512 + k]  = p7 * v1[i] / n1;
        A1[(size_t)n*1536 + 1024 + k] = p7 * k2s[k];
        A2[(size_t)n*1536 + k]        = p8 * c;
        A2[(size_t)n*1536 + 512 + k]  = p8 * v2[i] / n2;
        A2[(size_t)n*1536 + 1024 + k] = p8 * k1s[k];
    }
}

// ================================================================
// k_mid: blocks 0..1023   -> kb pass B (Transform attention)
//        blocks 1024..1535 -> fused mem GEMM split-K=16 partials
// (both depend only on k_elt; memory-bound + compute-bound co-schedule)
// ================================================================
__global__ __launch_bounds__(256) void k_mid(
    const float* __restrict__ kb, const float* __restrict__ g,
    const float* __restrict__ w_tr, const float* __restrict__ b_tr,
    float* __restrict__ aT,
    const float* __restrict__ A1, const float* __restrict__ A2,
    const float* __restrict__ W1, const float* __restrict__ W2,
    float* __restrict__ P2)
{
    __shared__ float As[16][68];
    __shared__ float Bs[16][68];
    const int t = threadIdx.x;

    if (blockIdx.x < 1024) {
        const int blk = blockIdx.x;
        const int n = blk >> 2, sp = blk & 3;
        const int wv = t >> 6, lane = t & 63;
        const int k0 = lane * 8;
        const int p0 = sp * 49;
        float gv[8], wt[8];
        {
            float4 a0 = ld4(g + (size_t)n*512 + k0), a1 = ld4(g + (size_t)n*512 + k0 + 4);
            gv[0]=a0.x; gv[1]=a0.y; gv[2]=a0.z; gv[3]=a0.w; gv[4]=a1.x; gv[5]=a1.y; gv[6]=a1.z; gv[7]=a1.w;
            float4 b0 = ld4(w_tr + k0), b1 = ld4(w_tr + k0 + 4);
            wt[0]=b0.x; wt[1]=b0.y; wt[2]=b0.z; wt[3]=b0.w; wt[4]=b1.x; wt[5]=b1.y; wt[6]=b1.z; wt[7]=b1.w;
        }
        const float bt = b_tr[0];
        const float* src0 = kb + (((size_t)n*HW + p0 + wv) * KBC + k0);
        float4 v0 = ld4(src0), v1 = ld4(src0 + 4);
        for (int pl = wv; pl < 49; pl += 4) {
            float4 n0, n1;
            if (pl + 4 < 49) {
                const float* ns = kb + (((size_t)n*HW + p0 + pl + 4) * KBC + k0);
                n0 = ld4(ns); n1 = ld4(ns + 4);
            }
            float kv[8] = {v0.x, v0.y, v0.z, v0.w, v1.x, v1.y, v1.z, v1.w};
            float sC = 0.f, sD = 0.f;
#pragma unroll
            for (int j = 0; j < 8; ++j) {
                const float u = kv[j] * gv[j];
                sC = fmaf(u, u, sC);
                sD = fmaf(u, wt[j], sD);
            }
#pragma unroll
            for (int m = 1; m < 64; m <<= 1) { sC += __shfl_xor(sC, m); sD += __shfl_xor(sD, m); }
            if (lane == 0) aT[(size_t)n*HW + p0 + pl] = sD / fmaxf(sqrtf(sC), EPSF) + bt;
            v0 = n0; v1 = n1;
        }
        return;
    }

    // ---- fused mem GEMM: [p7*A1 | p8*A2] @ vstack(W1,W2), KCHUNK=192, 16 splits ----
    const int idx = blockIdx.x - 1024;           // 0..511
    const int bn = (idx & 7) * 64;               // 512/64 = 8 col tiles
    const int bm = ((idx >> 3) & 3) * 64;        // 4 row tiles
    const int ks = idx >> 5;                     // 16 K splits
    const int mat = ks >> 3;
    const float* A = mat ? A2 : A1;
    const float* B = mat ? W2 : W1;
    const int kbase = ks * 192 - mat * 1536;

    const int tx = t & 15, ty = t >> 4;
    float acc[4][4] = {};
    const int ar = t >> 2, ac4 = (t & 3) * 4;
    const int br = t >> 4, bc4 = (t & 15) * 4;
    const float* Aptr = A + (size_t)(bm + ar) * 1536 + kbase + ac4;
    const float* Bptr = B + (size_t)(kbase + br) * 512 + bn + bc4;

    float4 aR = ld4(Aptr), bR = ld4(Bptr);
    for (int tile = 0; tile < 12; ++tile) {
        As[ac4+0][ar] = aR.x; As[ac4+1][ar] = aR.y; As[ac4+2][ar] = aR.z; As[ac4+3][ar] = aR.w;
        *reinterpret_cast<float4*>(&Bs[br][bc4]) = bR;
        __syncthreads();
        if (tile + 1 < 12) {
            aR = ld4(Aptr + (tile+1)*16);
            bR = ld4(Bptr + (size_t)(tile+1)*16*512);
        }
#pragma unroll
        for (int k = 0; k < 16; ++k) {
            float4 ra = *reinterpret_cast<const float4*>(&As[k][ty*4]);
            float4 rb = *reinterpret_cast<const float4*>(&Bs[k][tx*4]);
            const float av[4] = {ra.x, ra.y, ra.z, ra.w};
            const float bv[4] = {rb.x, rb.y, rb.z, rb.w};
#pragma unroll
            for (int i = 0; i < 4; ++i)
#pragma unroll
                for (int j = 0; j < 4; ++j)
                    acc[i][j] = fmaf(av[i], bv[j], acc[i][j]);
        }
        __syncthreads();
    }
#pragma unroll
    for (int i = 0; i < 4; ++i) {
        float4 v = make_float4(acc[i][0], acc[i][1], acc[i][2], acc[i][3]);
        *reinterpret_cast<float4*>(&P2[((size_t)ks*NB + bm + ty*4 + i) * 512 + bn + tx*4]) = v;
    }
}

// ================================================================
// k_back: blocks 0..127 -> mem_avg (reduce 16 gemm2 partials + biases + prev)
//         blocks 128..383 -> att_stack_avg + stack_ptr_avg
// ================================================================
__global__ __launch_bounds__(256) void k_back(
    const float* __restrict__ P2, const float* __restrict__ memprev,
    const float* __restrict__ prob,
    const float* __restrict__ mb1, const float* __restrict__ mb2,
    float* __restrict__ out_mem,
    const float* __restrict__ stk, const float* __restrict__ ptrp,
    const float* __restrict__ att1g, const float* __restrict__ att2g,
    const float* __restrict__ aFg, const float* __restrict__ aTg, const float* __restrict__ aSg,
    const float* __restrict__ fws, const float* __restrict__ bws, const float* __restrict__ fbws,
    const float* __restrict__ sf2ws, const float* __restrict__ sffbws,
    float* __restrict__ out_att, float* __restrict__ out_ptr)
{
    const int t = threadIdx.x;
    if (blockIdx.x < 128) {
        const size_t q = ((size_t)blockIdx.x * 256 + t) * 4;      // < 256*512
        const int n = (int)(q >> 9), j = (int)(q & 511);
        const float p0 = prob[n*9 + 0], p7 = prob[n*9 + 7], p8 = prob[n*9 + 8];
        float4 s = ld4(P2 + q);
#pragma unroll
        for (int sp = 1; sp < 16; ++sp) {
            float4 v = ld4(P2 + (size_t)sp*131072 + q);
            s.x += v.x; s.y += v.y; s.z += v.z; s.w += v.w;
        }
        float4 mp = ld4(memprev + q);
        float4 w1 = ld4(mb1 + j), w2 = ld4(mb2 + j);
        float4 o;
        o.x = p0*mp.x + s.x + p7*w1.x + p8*w2.x;
        o.y = p0*mp.y + s.y + p7*w1.y + p8*w2.y;
        o.z = p0*mp.z + s.z + p7*w1.z + p8*w2.z;
        o.w = p0*mp.w + s.w + p7*w1.w + p8*w2.w;
        *reinterpret_cast<float4*>(&out_mem[q]) = o;
        return;
    }

    const int n = blockIdx.x - 128;
    __shared__ float pp[8], f[8], b[8], fb[8], pr[9], sc2[2];
    if (t < 8) { pp[t] = ptrp[n*8+t]; f[t] = fws[n*8+t]; b[t] = bws[n*8+t]; fb[t] = fbws[n*8+t]; }
    if (t < 9) pr[t] = prob[n*9+t];
    if (t == 0) { sc2[0] = sf2ws[n]; sc2[1] = sffbws[n]; }
    __syncthreads();

    if (t < HW) {
        const size_t p = (size_t)n*HW + t;
        const float* spt = stk + p*8;
        float4 v0 = ld4(spt), v1 = ld4(spt+4);
        float s[8] = {v0.x, v0.y, v0.z, v0.w, v1.x, v1.y, v1.z, v1.w};
        const float a1 = att1g[p], a2 = att2g[p];
        const float vaF = aFg[p], vaT = aTg[p], vaS = aSg[p];
        const float mn = fminf(a1, a2), mx = fmaxf(a1, a2);
        float rf = 0.f, rf2 = 0.f, rfb = 0.f, rffb = 0.f;
#pragma unroll
        for (int l = 0; l < 8; ++l) {
            rf   = fmaf(s[l], f[l],        rf);
            rf2  = fmaf(s[l], f[l]*f[l],   rf2);
            rfb  = fmaf(s[l], fb[l],       rfb);
            rffb = fmaf(s[l], f[l]*fb[l],  rffb);
        }
        const float att2p = vaF*sc2[0] + rf  - rf2;
        const float att1p = vaF*sc2[1] + rfb - rffb;
        const float mnF = fminf(att1p, att2p);
        const float c48 = pr[4] + pr[8];
        float o[8];
#pragma unroll
        for (int l = 0; l < 8; ++l) {
            const float sl = s[l];
            const float stkF = vaF*f[l] + sl*(1.f - f[l]);
            float r = (pr[0] + pr[7]) * sl;
            r = fmaf(pr[1], stkF, r);
            r = fmaf(pr[2], vaT*pp[l] + sl*(1.f - pp[l]), r);
            r = fmaf(pr[3], mnF*fb[l] + stkF*(1.f - fb[l]), r);
            r = fmaf(c48,   mn*b[l] + sl*(1.f - b[l]), r);
            r = fmaf(pr[5], mx*b[l] + sl*(1.f - b[l]), r);
            r = fmaf(pr[6], vaS*f[l] + sl*(1.f - f[l]), r);
            o[l] = r;
        }
        *reinterpret_cast<float4*>(out_att + p*8)     = make_float4(o[0], o[1], o[2], o[3]);
        *reinterpret_cast<float4*>(out_att + p*8 + 4) = make_float4(o[4], o[5], o[6], o[7]);
    }

    if (t == 0) {
        const float cpp = pr[0] + pr[2] + pr[7];
        const float cf  = pr[1] + pr[6];
        const float cb  = pr[4] + pr[5] + pr[8];
        float pa[8];
        float m = -3.0e38f;
#pragma unroll
        for (int l = 0; l < 8; ++l) {
            pa[l] = cpp*pp[l] + cf*f[l] + cb*b[l] + pr[3]*fb[l];
            m = fmaxf(m, pa[l]);
        }
        float ssum = 0.f;
#pragma unroll
        for (int l = 0; l < 8; ++l) { pa[l] = __expf(pa[l] - m); ssum += pa[l]; }
#pragma unroll
        for (int l = 0; l < 8; ++l) out_ptr[n*8 + l] = pa[l] / ssum;
    }
}

// ================================================================
extern "C" void kernel_launch(void* const* d_in, const int* in_sizes, int n_in,
                              void* d_out, int out_size, void* d_ws, size_t ws_size,
                              hipStream_t stream)
{
    (void)in_sizes; (void)n_in; (void)out_size;
    const float* control = (const float*)d_in[0];
    const float* kb      = (const float*)d_in[1];
    const float* prob    = (const float*)d_in[2];
    const float* memprev = (const float*)d_in[3];
    const float* stk     = (const float*)d_in[4];
    const float* ptrp    = (const float*)d_in[5];
    const float* find_w  = (const float*)d_in[6];
    const float* find_b  = (const float*)d_in[7];
    const float* findc_w = (const float*)d_in[8];
    const float* findc_b = (const float*)d_in[9];
    const float* tr_w    = (const float*)d_in[10];
    const float* tr_b    = (const float*)d_in[11];
    const float* trc_w   = (const float*)d_in[12];
    const float* trc_b   = (const float*)d_in[13];
    const float* sc_w    = (const float*)d_in[14];
    const float* sc_b    = (const float*)d_in[15];
    const float* d1_w    = (const float*)d_in[16];
    const float* d1_b    = (const float*)d_in[17];
    const float* d1m_w   = (const float*)d_in[18];
    const float* d1m_b   = (const float*)d_in[19];
    const float* d2_w    = (const float*)d_in[20];
    const float* d2_b    = (const float*)d_in[21];
    const float* d2m_w   = (const float*)d_in[22];
    const float* d2m_b   = (const float*)d_in[23];

    if (ws_size < WS_FLOATS * sizeof(float)) return;

    float* ws    = (float*)d_ws;
    float* att1g = ws + OFF_ATT1;
    float* att2g = ws + OFF_ATT2;
    float* w1g   = ws + OFF_W1;
    float* w2g   = ws + OFF_W2;
    float* aF    = ws + OFF_AF;
    float* aT    = ws + OFF_AT;
    float* aS    = ws + OFF_AS;
    float* GP1   = ws + OFF_GP1;
    float* kpart = ws + OFF_KP;
    float* A1    = ws + OFF_A1;
    float* A2    = ws + OFF_A2;
    float* g     = ws + OFF_G;
    float* P2    = ws + OFF_P2;
    float* fws   = ws + OFF_PF;
    float* bws   = ws + OFF_PB;
    float* fbws  = ws + OFF_PFB;
    float* sf2   = ws + OFF_SF2;
    float* sffb  = ws + OFF_SFFB;

    float* out_att = (float*)d_out;
    float* out_ptr = out_att + (size_t)NB*HW*LSZ;
    float* out_mem = out_ptr + (size_t)NB*LSZ;

    // 1. k_att ∪ gemm1-partials
    k_front<<<256 + 512, 256, 0, stream>>>(
        stk, ptrp, att1g, att2g, w1g, w2g, fws, bws, fbws, sf2, sffb,
        control, find_w, tr_w, d1_w, d2_w, GP1);
    // 2. kb pass A (reduces its own c_find from GP1)
    k_kbA<<<NB*4, 256, 0, stream>>>(kb, GP1, find_b, findc_w, findc_b, sc_w, sc_b,
                                    w1g, w2g, aF, aS, kpart);
    // 3. katt reduce + c_tr/c_d1/c_d2 reduce + g/elts/A1'/A2'
    k_elt<<<NB, 256, 0, stream>>>(kpart, GP1, tr_b, d1_b, d2_b,
                                  control, prob, g, A1, A2);
    // 4. kb pass B ∪ fused mem-GEMM partials
    k_mid<<<1024 + 512, 256, 0, stream>>>(kb, g, trc_w, trc_b, aT,
                                          A1, A2, d1m_w, d2m_w, P2);
    // 5. mem_avg ∪ att_stack_avg/stack_ptr_avg
    k_back<<<128 + 256, 256, 0, stream>>>(P2, memprev, prob, d1m_b, d2m_b, out_mem,
                                          stk, ptrp, att1g, att2g, aF, aT, aS,
                                          fws, bws, fbws, sf2, sffb, out_att, out_ptr);
}